// Round 2
// baseline (982.961 us; speedup 1.0000x reference)
//
#include <hip/hip_runtime.h>

#define T_TOK 8192
#define DD    1024
#define EE    8
#define HH    2560
#define PAIR_CAP (T_TOK*2 + 128)
#define MT_MAX 64          // worst-case token tiles per expert (8192/128)
#define NT1   (HH/64)      // 40
#define NT2   (DD/128)     // 8

typedef __attribute__((ext_vector_type(8))) short bf16x8;
typedef __attribute__((ext_vector_type(4))) float f32x4;

__device__ __forceinline__ unsigned short f2b(float f) {
  union { float f; unsigned u; } v; v.f = f;
  unsigned r = v.u + 0x7FFFu + ((v.u >> 16) & 1u);   // RNE
  return (unsigned short)(r >> 16);
}

// async global->LDS, 16B per lane. LDS dest must be wave-uniform base (+lane*16 implicit).
__device__ __forceinline__ void async16(const void* g, void* l) {
  __builtin_amdgcn_global_load_lds(
      (const __attribute__((address_space(1))) unsigned int*)(unsigned long long)g,
      (__attribute__((address_space(3))) unsigned int*)l,
      16, 0, 0);
}

__global__ void zero_ints(int* a, int n) {
  int i = threadIdx.x;
  if (i < n) a[i] = 0;
}

__global__ void conv_bf16(const float* __restrict__ s, unsigned short* __restrict__ d, int n4) {
  int i = blockIdx.x * blockDim.x + threadIdx.x;
  if (i >= n4) return;
  float4 v = ((const float4*)s)[i];
  ushort4 o;
  o.x = f2b(v.x); o.y = f2b(v.y); o.z = f2b(v.z); o.w = f2b(v.w);
  ((ushort4*)d)[i] = o;
}

// one wave per token; Wr (8x1024 fp32 = 32KB) in LDS. also emits xb (bf16 of x).
__global__ __launch_bounds__(256) void router(
    const float* __restrict__ x, const float* __restrict__ Wr,
    unsigned short* __restrict__ xb,
    float* __restrict__ o_logits, float* __restrict__ o_probs, float* __restrict__ o_topi,
    int* __restrict__ top_e, float* __restrict__ top_p, int* __restrict__ counts)
{
  __shared__ float sWr[EE * DD];
  int tid = threadIdx.x;
  const float4* w4 = (const float4*)Wr;
  float4* s4 = (float4*)sWr;
  for (int i = tid; i < EE * DD / 4; i += 256) s4[i] = w4[i];
  __syncthreads();

  int wv = tid >> 6, lane = tid & 63;
  int t = blockIdx.x * 4 + wv;
  const float4* xt4 = (const float4*)(x + (size_t)t * DD);
  ushort4* xbt = (ushort4*)(xb + (size_t)t * DD);

  float acc[EE];
#pragma unroll
  for (int e = 0; e < EE; e++) acc[e] = 0.f;
#pragma unroll
  for (int p = 0; p < 4; p++) {
    float4 v = xt4[p * 64 + lane];
    ushort4 o;
    o.x = f2b(v.x); o.y = f2b(v.y); o.z = f2b(v.z); o.w = f2b(v.w);
    xbt[p * 64 + lane] = o;
    int d = (p * 64 + lane) * 4;
#pragma unroll
    for (int e = 0; e < EE; e++) {
      const float* wr = &sWr[e * DD + d];
      acc[e] += v.x * wr[0] + v.y * wr[1] + v.z * wr[2] + v.w * wr[3];
    }
  }
#pragma unroll
  for (int e = 0; e < EE; e++) {
#pragma unroll
    for (int off = 32; off; off >>= 1) acc[e] += __shfl_down(acc[e], off);
  }
  if (lane == 0) {
    float mx = acc[0];
#pragma unroll
    for (int e = 1; e < EE; e++) mx = fmaxf(mx, acc[e]);
    float p[EE]; float sum = 0.f;
#pragma unroll
    for (int e = 0; e < EE; e++) { p[e] = __expf(acc[e] - mx); sum += p[e]; }
    float inv = 1.f / sum;
#pragma unroll
    for (int e = 0; e < EE; e++) {
      p[e] *= inv;
      o_logits[(size_t)t * EE + e] = acc[e];
      o_probs [(size_t)t * EE + e] = p[e];
    }
    // top-2, ties -> lowest index (matches jax.lax.top_k)
    int i0 = 0;
#pragma unroll
    for (int e = 1; e < EE; e++) if (p[e] > p[i0]) i0 = e;
    int i1 = (i0 == 0) ? 1 : 0;
#pragma unroll
    for (int e = 0; e < EE; e++) if (e != i0 && p[e] > p[i1]) i1 = e;

    o_topi[t * 2 + 0] = (float)i0;
    o_topi[t * 2 + 1] = (float)i1;
    top_e[t * 2 + 0] = i0; top_e[t * 2 + 1] = i1;
    top_p[t * 2 + 0] = p[i0]; top_p[t * 2 + 1] = p[i1];
    atomicAdd(&counts[i0], 1);
    atomicAdd(&counts[i1], 1);
  }
}

__global__ void mk_offsets(const int* __restrict__ counts, int* __restrict__ offsets,
                           int* __restrict__ cursors) {
  if (threadIdx.x == 0) {
    int s = 0;
    for (int e = 0; e < EE; e++) { offsets[e] = s; s += counts[e]; }
  }
  if (threadIdx.x < EE) cursors[threadIdx.x] = 0;
}

__global__ void scatter(const int* __restrict__ top_e,
                        const int* __restrict__ offsets, int* __restrict__ cursors,
                        int* __restrict__ list, int* __restrict__ slot) {
  int t = blockIdx.x * blockDim.x + threadIdx.x;
  if (t >= T_TOK) return;
#pragma unroll
  for (int k = 0; k < 2; k++) {
    int e = top_e[t * 2 + k];
    int pos = atomicAdd(&cursors[e], 1);
    int dst = offsets[e] + pos;
    list[dst] = t;
    slot[t * 2 + k] = dst;     // token -> pair-row mapping for combine
  }
}

// C = gathered_x[list] @ {Wg[e],Wu[e]}^T, fused h = silu(g)*u -> bf16 hbuf
// block tile: M=128 tokens x N=64 h-cols (dual acc: gate+up). 4 waves, each 64x32.
// BK=32, DOUBLE-buffered LDS (32KB total -> same occupancy as single/BK64).
// rows are 4x16B chunks; physical chunk j of row r holds logical j^((r>>1)&3)
// (pre-swizzled global source, linear LDS dest, swizzled ds_read). 16-lane phase
// analysis: byte%128 hits 8 slots with 2 lanes each -> 2-way = conflict-free.
// stage(next) issued BEFORE compute(cur): vmcnt(0) drain at the barrier waits on
// loads that had a full compute phase in flight (minimal T3 overlap).
__global__ __launch_bounds__(256) void gemm_gateup(
    const unsigned short* __restrict__ xb,
    const unsigned short* __restrict__ Wgb,
    const unsigned short* __restrict__ Wub,
    const int* __restrict__ list, const int* __restrict__ offsets,
    const int* __restrict__ counts,
    unsigned short* __restrict__ hbuf)
{
  int bx = blockIdx.x;
  int e = bx / (MT_MAX * NT1);
  int rem = bx - e * (MT_MAX * NT1);
  int mt = rem / NT1;
  int nt = rem - mt * NT1;
  int n_e = counts[e];
  if (mt * 128 >= n_e) return;
  int off_e = offsets[e];

  __shared__ unsigned short sA [2][128 * 32];  // 8KB x2
  __shared__ unsigned short sBg[2][ 64 * 32];  // 4KB x2
  __shared__ unsigned short sBu[2][ 64 * 32];  // 4KB x2

  int tid = threadIdx.x, wv = tid >> 6, lane = tid & 63;
  const unsigned short* wg_e = Wgb + (size_t)e * HH * DD;
  const unsigned short* wu_e = Wub + (size_t)e * HH * DD;

  // A: 512 16B-chunks (4/row), 2 rounds of 256. chunk c -> row c>>2, phys chunk c&3
  size_t aBase[2];
#pragma unroll
  for (int i = 0; i < 2; i++) {
    int c = i * 256 + tid;
    int r = c >> 2, j = c & 3;
    int jj = j ^ ((r >> 1) & 3);
    int idx = mt * 128 + r;
    if (idx >= n_e) idx = n_e - 1;          // clamp; epilogue masks
    int tok = list[off_e + idx];
    aBase[i] = (size_t)tok * DD + (size_t)(jj * 8);
  }
  // B: 256 chunks each, 1 round (same source offsets for gate & up)
  size_t bBase;
  {
    int r = tid >> 2, j = tid & 3;
    int jj = j ^ ((r >> 1) & 3);
    bBase = (size_t)(nt * 64 + r) * DD + (size_t)(jj * 8);
  }

  f32x4 accg[4][2] = {};
  f32x4 accu[4][2] = {};
  int wm = (wv >> 1) * 64, wn = (wv & 1) * 32;

  auto stage = [&](int b, int k0) {
    async16(xb  + aBase[0] + k0, &sA [b][(      wv * 64) * 8]);
    async16(xb  + aBase[1] + k0, &sA [b][(256 + wv * 64) * 8]);
    async16(wg_e + bBase   + k0, &sBg[b][(      wv * 64) * 8]);
    async16(wu_e + bBase   + k0, &sBu[b][(      wv * 64) * 8]);
  };

  stage(0, 0);
  int cur = 0;
  int q = lane >> 4;
  for (int k0 = 0; k0 < DD; k0 += 32) {
    __syncthreads();                       // drains cur's loads + prev ds_reads
    if (k0 + 32 < DD) stage(cur ^ 1, k0 + 32);

    bf16x8 af[4], bg[2], bu[2];
#pragma unroll
    for (int fi = 0; fi < 4; fi++) {
      int r = wm + fi * 16 + (lane & 15);
      int ch = q ^ ((r >> 1) & 3);
      af[fi] = *(const bf16x8*)&sA[cur][r * 32 + ch * 8];
    }
#pragma unroll
    for (int fj = 0; fj < 2; fj++) {
      int r = wn + fj * 16 + (lane & 15);
      int ch = q ^ ((r >> 1) & 3);
      bg[fj] = *(const bf16x8*)&sBg[cur][r * 32 + ch * 8];
      bu[fj] = *(const bf16x8*)&sBu[cur][r * 32 + ch * 8];
    }
#pragma unroll
    for (int fi = 0; fi < 4; fi++)
#pragma unroll
      for (int fj = 0; fj < 2; fj++) {
        accg[fi][fj] = __builtin_amdgcn_mfma_f32_16x16x32_bf16(af[fi], bg[fj], accg[fi][fj], 0, 0, 0);
        accu[fi][fj] = __builtin_amdgcn_mfma_f32_16x16x32_bf16(af[fi], bu[fj], accu[fi][fj], 0, 0, 0);
      }
    cur ^= 1;
  }

  // epilogue: h = silu(g)*u, C/D layout: col=lane&15, row=(lane>>4)*4+r
#pragma unroll
  for (int fi = 0; fi < 4; fi++) {
    int mBase = mt * 128 + wm + fi * 16 + ((lane >> 4) << 2);
#pragma unroll
    for (int fj = 0; fj < 2; fj++) {
      int col = nt * 64 + wn + fj * 16 + (lane & 15);
#pragma unroll
      for (int r = 0; r < 4; r++) {
        int m = mBase + r;
        if (m < n_e) {
          float g = accg[fi][fj][r];
          float u = accu[fi][fj][r];
          float hv = g / (1.f + __expf(-g)) * u;
          hbuf[(size_t)(off_e + m) * HH + col] = f2b(hv);
        }
      }
    }
  }
}

// tmp[pair] = h[pair] @ Wd[e]^T (UNweighted, no atomics). block 128x128, 4 waves each 64x64.
// BK=32 double-buffered (32KB), same swizzle + prefetch structure as gateup.
__global__ __launch_bounds__(256) void gemm_down(
    const unsigned short* __restrict__ hbuf,
    const unsigned short* __restrict__ Wdb,
    const int* __restrict__ offsets,
    const int* __restrict__ counts,
    float* __restrict__ tmp)
{
  int bx = blockIdx.x;
  int e = bx / (MT_MAX * NT2);
  int rem = bx - e * (MT_MAX * NT2);
  int mt = rem / NT2;
  int nt = rem - mt * NT2;
  int n_e = counts[e];
  if (mt * 128 >= n_e) return;
  int off_e = offsets[e];

  __shared__ unsigned short sA[2][128 * 32];  // 8KB x2
  __shared__ unsigned short sB[2][128 * 32];  // 8KB x2
  int tid = threadIdx.x, wv = tid >> 6, lane = tid & 63;
  const unsigned short* wd_e = Wdb + (size_t)e * DD * HH;

  size_t aBase[2], bBase[2];
#pragma unroll
  for (int i = 0; i < 2; i++) {
    int c = i * 256 + tid;
    int r = c >> 2, j = c & 3;
    int jj = j ^ ((r >> 1) & 3);
    aBase[i] = (size_t)(off_e + mt * 128 + r) * HH + (size_t)(jj * 8);  // rows >= n_e read junk; masked below
    bBase[i] = (size_t)(nt * 128 + r) * HH + (size_t)(jj * 8);
  }

  f32x4 acc[4][4] = {};
  int wm = (wv >> 1) * 64, wn = (wv & 1) * 64;

  auto stage = [&](int b, int k0) {
    async16(hbuf + aBase[0] + k0, &sA[b][(      wv * 64) * 8]);
    async16(hbuf + aBase[1] + k0, &sA[b][(256 + wv * 64) * 8]);
    async16(wd_e + bBase[0] + k0, &sB[b][(      wv * 64) * 8]);
    async16(wd_e + bBase[1] + k0, &sB[b][(256 + wv * 64) * 8]);
  };

  stage(0, 0);
  int cur = 0;
  int q = lane >> 4;
  for (int k0 = 0; k0 < HH; k0 += 32) {
    __syncthreads();
    if (k0 + 32 < HH) stage(cur ^ 1, k0 + 32);

    bf16x8 af[4], bfr[4];
#pragma unroll
    for (int f = 0; f < 4; f++) {
      int ra = wm + f * 16 + (lane & 15);
      int ca = q ^ ((ra >> 1) & 3);
      af[f] = *(const bf16x8*)&sA[cur][ra * 32 + ca * 8];
      int rb = wn + f * 16 + (lane & 15);
      int cb = q ^ ((rb >> 1) & 3);
      bfr[f] = *(const bf16x8*)&sB[cur][rb * 32 + cb * 8];
    }
#pragma unroll
    for (int fi = 0; fi < 4; fi++)
#pragma unroll
      for (int fj = 0; fj < 4; fj++)
        acc[fi][fj] = __builtin_amdgcn_mfma_f32_16x16x32_bf16(af[fi], bfr[fj], acc[fi][fj], 0, 0, 0);
    cur ^= 1;
  }

#pragma unroll
  for (int fi = 0; fi < 4; fi++) {
    int mBase = mt * 128 + wm + fi * 16 + ((lane >> 4) << 2);
#pragma unroll
    for (int r = 0; r < 4; r++) {
      int m = mBase + r;
      if (m < n_e) {
        float* orow = tmp + (size_t)(off_e + m) * DD + nt * 128 + wn;
#pragma unroll
        for (int fj = 0; fj < 4; fj++)
          orow[fj * 16 + (lane & 15)] = acc[fi][fj][r];
      }
    }
  }
}

// out[t] = p0*tmp[slot0] + p1*tmp[slot1]. one block per token, float4 per thread.
__global__ __launch_bounds__(256) void combine(
    const float* __restrict__ tmp, const int* __restrict__ slot,
    const float* __restrict__ top_p, float* __restrict__ out)
{
  int t = blockIdx.x, d = threadIdx.x;             // DD/4 == 256
  int s0 = slot[t * 2 + 0], s1 = slot[t * 2 + 1];
  float p0 = top_p[t * 2 + 0], p1 = top_p[t * 2 + 1];
  float4 a = ((const float4*)(tmp + (size_t)s0 * DD))[d];
  float4 b = ((const float4*)(tmp + (size_t)s1 * DD))[d];
  float4 o;
  o.x = p0 * a.x + p1 * b.x;
  o.y = p0 * a.y + p1 * b.y;
  o.z = p0 * a.z + p1 * b.z;
  o.w = p0 * a.w + p1 * b.w;
  ((float4*)(out + (size_t)t * DD))[d] = o;
}

extern "C" void kernel_launch(void* const* d_in, const int* in_sizes, int n_in,
                              void* d_out, int out_size, void* d_ws, size_t ws_size,
                              hipStream_t stream) {
  const float* x  = (const float*)d_in[0];
  const float* Wr = (const float*)d_in[1];
  const float* Wg = (const float*)d_in[2];
  const float* Wu = (const float*)d_in[3];
  const float* Wd = (const float*)d_in[4];

  float* out      = (float*)d_out;
  float* o_logits = out + (size_t)T_TOK * DD;
  float* o_probs  = o_logits + (size_t)T_TOK * EE;
  float* o_topi   = o_probs + (size_t)T_TOK * EE;

  char* w = (char*)d_ws;
  auto alloc = [&](size_t bytes) {
    char* p = w;
    w += (bytes + 255) & ~(size_t)255;
    return p;
  };
  unsigned short* Wgb = (unsigned short*)alloc((size_t)EE * HH * DD * 2);  // 41.9MB
  unsigned short* Wub = (unsigned short*)alloc((size_t)EE * HH * DD * 2);  // 41.9MB
  unsigned short* Wdb = (unsigned short*)alloc((size_t)EE * DD * HH * 2);
  unsigned short* xb  = (unsigned short*)alloc((size_t)T_TOK * DD * 2);
  unsigned short* hb  = (unsigned short*)alloc((size_t)PAIR_CAP * HH * 2);
  int*   top_e   = (int*)  alloc((size_t)T_TOK * 2 * 4);
  float* top_p   = (float*)alloc((size_t)T_TOK * 2 * 4);
  int*   counts  = (int*)  alloc(64);
  int*   offsets = (int*)  alloc(64);
  int*   cursors = (int*)  alloc(64);
  int*   list    = (int*)  alloc((size_t)PAIR_CAP * 4);
  int*   slot    = (int*)  alloc((size_t)T_TOK * 2 * 4);

  // tmp (pair outputs, fp32, 67.6MB) aliases Wgb+Wub (83.9MB) — dead after gemm_gateup.
  // stream-ordered: conv writes Wgb/Wub -> gateup reads -> gemm_down overwrites as tmp
  // -> combine reads tmp -> (next replay) conv rewrites. safe on a single stream.
  float* tmp = (float*)Wgb;

  zero_ints<<<1, 64, 0, stream>>>(counts, EE);
  {
    int nw4 = EE * HH * DD / 4;
    conv_bf16<<<(nw4 + 255) / 256, 256, 0, stream>>>(Wg, Wgb, nw4);
    conv_bf16<<<(nw4 + 255) / 256, 256, 0, stream>>>(Wu, Wub, nw4);
    conv_bf16<<<(nw4 + 255) / 256, 256, 0, stream>>>(Wd, Wdb, nw4);
  }
  router<<<T_TOK / 4, 256, 0, stream>>>(x, Wr, xb, o_logits, o_probs, o_topi, top_e, top_p, counts);
  mk_offsets<<<1, 64, 0, stream>>>(counts, offsets, cursors);
  scatter<<<T_TOK / 256, 256, 0, stream>>>(top_e, offsets, cursors, list, slot);
  gemm_gateup<<<EE * MT_MAX * NT1, 256, 0, stream>>>(xb, Wgb, Wub, list, offsets, counts, hb);
  gemm_down<<<EE * MT_MAX * NT2, 256, 0, stream>>>(hb, Wdb, offsets, counts, tmp);
  combine<<<T_TOK, 256, 0, stream>>>(tmp, slot, top_p, out);
}

// Round 3
// 899.436 us; speedup vs baseline: 1.0929x; 1.0929x over previous
//
#include <hip/hip_runtime.h>

#define T_TOK 8192
#define DD    1024
#define EE    8
#define HH    2560
#define PAIR_CAP (T_TOK*2 + 128)
#define MT_MAX 64          // worst-case token tiles per expert (8192/128)
#define NT1   (HH/64)      // 40
#define NT2   (DD/128)     // 8

typedef __attribute__((ext_vector_type(8))) short bf16x8;
typedef __attribute__((ext_vector_type(4))) float f32x4;

__device__ __forceinline__ unsigned short f2b(float f) {
  union { float f; unsigned u; } v; v.f = f;
  unsigned r = v.u + 0x7FFFu + ((v.u >> 16) & 1u);   // RNE
  return (unsigned short)(r >> 16);
}

// async global->LDS, 16B per lane. LDS dest must be wave-uniform base (+lane*16 implicit).
__device__ __forceinline__ void async16(const void* g, void* l) {
  __builtin_amdgcn_global_load_lds(
      (const __attribute__((address_space(1))) unsigned int*)(unsigned long long)g,
      (__attribute__((address_space(3))) unsigned int*)l,
      16, 0, 0);
}

__global__ void zero_ints(int* a, int n) {
  int i = threadIdx.x;
  if (i < n) a[i] = 0;
}

// one kernel converts Wg, Wu, Wd (same element count) — blockIdx.y selects tensor
__global__ void conv_bf16_3(const float* __restrict__ s0, const float* __restrict__ s1,
                            const float* __restrict__ s2,
                            unsigned short* __restrict__ d0, unsigned short* __restrict__ d1,
                            unsigned short* __restrict__ d2, int n4) {
  int i = blockIdx.x * blockDim.x + threadIdx.x;
  if (i >= n4) return;
  const float* s = (blockIdx.y == 0) ? s0 : (blockIdx.y == 1) ? s1 : s2;
  unsigned short* d = (blockIdx.y == 0) ? d0 : (blockIdx.y == 1) ? d1 : d2;
  float4 v = ((const float4*)s)[i];
  ushort4 o;
  o.x = f2b(v.x); o.y = f2b(v.y); o.z = f2b(v.z); o.w = f2b(v.w);
  ((ushort4*)d)[i] = o;
}

// one wave per token; Wr (8x1024 fp32 = 32KB) in LDS. also emits xb (bf16 of x).
__global__ __launch_bounds__(256) void router(
    const float* __restrict__ x, const float* __restrict__ Wr,
    unsigned short* __restrict__ xb,
    float* __restrict__ o_logits, float* __restrict__ o_probs, float* __restrict__ o_topi,
    int* __restrict__ top_e, float* __restrict__ top_p, int* __restrict__ counts)
{
  __shared__ float sWr[EE * DD];
  int tid = threadIdx.x;
  const float4* w4 = (const float4*)Wr;
  float4* s4 = (float4*)sWr;
  for (int i = tid; i < EE * DD / 4; i += 256) s4[i] = w4[i];
  __syncthreads();

  int wv = tid >> 6, lane = tid & 63;
  int t = blockIdx.x * 4 + wv;
  const float4* xt4 = (const float4*)(x + (size_t)t * DD);
  ushort4* xbt = (ushort4*)(xb + (size_t)t * DD);

  float acc[EE];
#pragma unroll
  for (int e = 0; e < EE; e++) acc[e] = 0.f;
#pragma unroll
  for (int p = 0; p < 4; p++) {
    float4 v = xt4[p * 64 + lane];
    ushort4 o;
    o.x = f2b(v.x); o.y = f2b(v.y); o.z = f2b(v.z); o.w = f2b(v.w);
    xbt[p * 64 + lane] = o;
    int d = (p * 64 + lane) * 4;
#pragma unroll
    for (int e = 0; e < EE; e++) {
      const float* wr = &sWr[e * DD + d];
      acc[e] += v.x * wr[0] + v.y * wr[1] + v.z * wr[2] + v.w * wr[3];
    }
  }
#pragma unroll
  for (int e = 0; e < EE; e++) {
#pragma unroll
    for (int off = 32; off; off >>= 1) acc[e] += __shfl_down(acc[e], off);
  }
  if (lane == 0) {
    float mx = acc[0];
#pragma unroll
    for (int e = 1; e < EE; e++) mx = fmaxf(mx, acc[e]);
    float p[EE]; float sum = 0.f;
#pragma unroll
    for (int e = 0; e < EE; e++) { p[e] = __expf(acc[e] - mx); sum += p[e]; }
    float inv = 1.f / sum;
#pragma unroll
    for (int e = 0; e < EE; e++) {
      p[e] *= inv;
      o_logits[(size_t)t * EE + e] = acc[e];
      o_probs [(size_t)t * EE + e] = p[e];
    }
    // top-2, ties -> lowest index (matches jax.lax.top_k)
    int i0 = 0;
#pragma unroll
    for (int e = 1; e < EE; e++) if (p[e] > p[i0]) i0 = e;
    int i1 = (i0 == 0) ? 1 : 0;
#pragma unroll
    for (int e = 0; e < EE; e++) if (e != i0 && p[e] > p[i1]) i1 = e;

    o_topi[t * 2 + 0] = (float)i0;
    o_topi[t * 2 + 1] = (float)i1;
    top_e[t * 2 + 0] = i0; top_e[t * 2 + 1] = i1;
    top_p[t * 2 + 0] = p[i0]; top_p[t * 2 + 1] = p[i1];
    atomicAdd(&counts[i0], 1);
    atomicAdd(&counts[i1], 1);
  }
}

__global__ void mk_offsets(const int* __restrict__ counts, int* __restrict__ offsets,
                           int* __restrict__ cursors) {
  if (threadIdx.x == 0) {
    int s = 0;
    for (int e = 0; e < EE; e++) { offsets[e] = s; s += counts[e]; }
  }
  if (threadIdx.x < EE) cursors[threadIdx.x] = 0;
}

__global__ void scatter(const int* __restrict__ top_e,
                        const int* __restrict__ offsets, int* __restrict__ cursors,
                        int* __restrict__ list, int* __restrict__ slot) {
  int t = blockIdx.x * blockDim.x + threadIdx.x;
  if (t >= T_TOK) return;
#pragma unroll
  for (int k = 0; k < 2; k++) {
    int e = top_e[t * 2 + k];
    int pos = atomicAdd(&cursors[e], 1);
    int dst = offsets[e] + pos;
    list[dst] = t;
    slot[t * 2 + k] = dst;     // token -> pair-row mapping for combine
  }
}

// C = gathered_x[list] @ {Wg[e],Wu[e]}^T, fused h = silu(g)*u -> bf16 hbuf
// block tile: M=128 tokens x N=64 h-cols (dual acc: gate+up). 4 waves, each 64x32.
// BK=32, 2 LDS buffers (32KB), COUNTED-vmcnt pipeline with prefetch distance 2:
//   iter t: vmcnt(4) waits ONLY tile t's 4 loads (tile t+1 stays in flight),
//   barrier; ds_read; lgkmcnt(0); barrier; stage tile t+2 into this buffer; MFMA.
// Loads get ~2 full compute phases to land; no full vmcnt(0) drain in the loop.
// Swizzle (round-2, verified conflict-free): phys chunk j of row r = logical j^((r>>1)&3).
__global__ __launch_bounds__(256) void gemm_gateup(
    const unsigned short* __restrict__ xb,
    const unsigned short* __restrict__ Wgb,
    const unsigned short* __restrict__ Wub,
    const int* __restrict__ list, const int* __restrict__ offsets,
    const int* __restrict__ counts,
    unsigned short* __restrict__ hbuf)
{
  int bx = blockIdx.x;
  int e = bx / (MT_MAX * NT1);
  int rem = bx - e * (MT_MAX * NT1);
  int mt = rem / NT1;
  int nt = rem - mt * NT1;
  int n_e = counts[e];
  if (mt * 128 >= n_e) return;
  int off_e = offsets[e];

  __shared__ unsigned short sA [2][128 * 32];  // 8KB x2
  __shared__ unsigned short sBg[2][ 64 * 32];  // 4KB x2
  __shared__ unsigned short sBu[2][ 64 * 32];  // 4KB x2

  int tid = threadIdx.x, wv = tid >> 6, lane = tid & 63;
  const unsigned short* wg_e = Wgb + (size_t)e * HH * DD;
  const unsigned short* wu_e = Wub + (size_t)e * HH * DD;

  // A: 512 16B-chunks (4/row), 2 rounds of 256. chunk c -> row c>>2, phys chunk c&3
  size_t aBase[2];
#pragma unroll
  for (int i = 0; i < 2; i++) {
    int c = i * 256 + tid;
    int r = c >> 2, j = c & 3;
    int jj = j ^ ((r >> 1) & 3);
    int idx = mt * 128 + r;
    if (idx >= n_e) idx = n_e - 1;          // clamp; epilogue masks
    int tok = list[off_e + idx];
    aBase[i] = (size_t)tok * DD + (size_t)(jj * 8);
  }
  // B: 256 chunks each, 1 round (same source offsets for gate & up)
  size_t bBase;
  {
    int r = tid >> 2, j = tid & 3;
    int jj = j ^ ((r >> 1) & 3);
    bBase = (size_t)(nt * 64 + r) * DD + (size_t)(jj * 8);
  }

  f32x4 accg[4][2] = {};
  f32x4 accu[4][2] = {};
  int wm = (wv >> 1) * 64, wn = (wv & 1) * 32;

  auto stage = [&](int b, int k0) {        // 4 loads per thread, always
    async16(xb  + aBase[0] + k0, &sA [b][(      wv * 64) * 8]);
    async16(xb  + aBase[1] + k0, &sA [b][(256 + wv * 64) * 8]);
    async16(wg_e + bBase   + k0, &sBg[b][(      wv * 64) * 8]);
    async16(wu_e + bBase   + k0, &sBu[b][(      wv * 64) * 8]);
  };

  const int NK = DD / 32;  // 32
  stage(0, 0);
  stage(1, 32);
  int q = lane >> 4;
  for (int t = 0; t < NK; ++t) {
    int cur = t & 1;
    if (t == NK - 1) asm volatile("s_waitcnt vmcnt(0)" ::: "memory");
    else             asm volatile("s_waitcnt vmcnt(4)" ::: "memory");
    __builtin_amdgcn_s_barrier();          // tile t resident in buf[cur] for all waves

    bf16x8 af[4], bg[2], bu[2];
#pragma unroll
    for (int fi = 0; fi < 4; fi++) {
      int r = wm + fi * 16 + (lane & 15);
      int ch = q ^ ((r >> 1) & 3);
      af[fi] = *(const bf16x8*)&sA[cur][r * 32 + ch * 8];
    }
#pragma unroll
    for (int fj = 0; fj < 2; fj++) {
      int r = wn + fj * 16 + (lane & 15);
      int ch = q ^ ((r >> 1) & 3);
      bg[fj] = *(const bf16x8*)&sBg[cur][r * 32 + ch * 8];
      bu[fj] = *(const bf16x8*)&sBu[cur][r * 32 + ch * 8];
    }
    asm volatile("s_waitcnt lgkmcnt(0)" ::: "memory");
    __builtin_amdgcn_sched_barrier(0);
    __builtin_amdgcn_s_barrier();          // all waves done reading buf[cur]
    if (t + 2 < NK) stage(cur, (t + 2) * 32);

    __builtin_amdgcn_s_setprio(1);
#pragma unroll
    for (int fi = 0; fi < 4; fi++)
#pragma unroll
      for (int fj = 0; fj < 2; fj++) {
        accg[fi][fj] = __builtin_amdgcn_mfma_f32_16x16x32_bf16(af[fi], bg[fj], accg[fi][fj], 0, 0, 0);
        accu[fi][fj] = __builtin_amdgcn_mfma_f32_16x16x32_bf16(af[fi], bu[fj], accu[fi][fj], 0, 0, 0);
      }
    __builtin_amdgcn_s_setprio(0);
  }

  // epilogue: h = silu(g)*u, C/D layout: col=lane&15, row=(lane>>4)*4+r
#pragma unroll
  for (int fi = 0; fi < 4; fi++) {
    int mBase = mt * 128 + wm + fi * 16 + ((lane >> 4) << 2);
#pragma unroll
    for (int fj = 0; fj < 2; fj++) {
      int col = nt * 64 + wn + fj * 16 + (lane & 15);
#pragma unroll
      for (int r = 0; r < 4; r++) {
        int m = mBase + r;
        if (m < n_e) {
          float g = accg[fi][fj][r];
          float u = accu[fi][fj][r];
          float hv = g / (1.f + __expf(-g)) * u;
          hbuf[(size_t)(off_e + m) * HH + col] = f2b(hv);
        }
      }
    }
  }
}

// tmp[pair] = h[pair] @ Wd[e]^T (UNweighted, no atomics). block 128x128, 4 waves each 64x64.
// Same counted-vmcnt distance-2 pipeline as gateup. NK = 80.
__global__ __launch_bounds__(256) void gemm_down(
    const unsigned short* __restrict__ hbuf,
    const unsigned short* __restrict__ Wdb,
    const int* __restrict__ offsets,
    const int* __restrict__ counts,
    float* __restrict__ tmp)
{
  int bx = blockIdx.x;
  int e = bx / (MT_MAX * NT2);
  int rem = bx - e * (MT_MAX * NT2);
  int mt = rem / NT2;
  int nt = rem - mt * NT2;
  int n_e = counts[e];
  if (mt * 128 >= n_e) return;
  int off_e = offsets[e];

  __shared__ unsigned short sA[2][128 * 32];  // 8KB x2
  __shared__ unsigned short sB[2][128 * 32];  // 8KB x2
  int tid = threadIdx.x, wv = tid >> 6, lane = tid & 63;
  const unsigned short* wd_e = Wdb + (size_t)e * DD * HH;

  size_t aBase[2], bBase[2];
#pragma unroll
  for (int i = 0; i < 2; i++) {
    int c = i * 256 + tid;
    int r = c >> 2, j = c & 3;
    int jj = j ^ ((r >> 1) & 3);
    aBase[i] = (size_t)(off_e + mt * 128 + r) * HH + (size_t)(jj * 8);  // rows >= n_e read junk; masked below
    bBase[i] = (size_t)(nt * 128 + r) * HH + (size_t)(jj * 8);
  }

  f32x4 acc[4][4] = {};
  int wm = (wv >> 1) * 64, wn = (wv & 1) * 64;

  auto stage = [&](int b, int k0) {        // 4 loads per thread, always
    async16(hbuf + aBase[0] + k0, &sA[b][(      wv * 64) * 8]);
    async16(hbuf + aBase[1] + k0, &sA[b][(256 + wv * 64) * 8]);
    async16(wd_e + bBase[0] + k0, &sB[b][(      wv * 64) * 8]);
    async16(wd_e + bBase[1] + k0, &sB[b][(256 + wv * 64) * 8]);
  };

  const int NK = HH / 32;  // 80
  stage(0, 0);
  stage(1, 32);
  int q = lane >> 4;
  for (int t = 0; t < NK; ++t) {
    int cur = t & 1;
    if (t == NK - 1) asm volatile("s_waitcnt vmcnt(0)" ::: "memory");
    else             asm volatile("s_waitcnt vmcnt(4)" ::: "memory");
    __builtin_amdgcn_s_barrier();

    bf16x8 af[4], bfr[4];
#pragma unroll
    for (int f = 0; f < 4; f++) {
      int ra = wm + f * 16 + (lane & 15);
      int ca = q ^ ((ra >> 1) & 3);
      af[f] = *(const bf16x8*)&sA[cur][ra * 32 + ca * 8];
      int rb = wn + f * 16 + (lane & 15);
      int cb = q ^ ((rb >> 1) & 3);
      bfr[f] = *(const bf16x8*)&sB[cur][rb * 32 + cb * 8];
    }
    asm volatile("s_waitcnt lgkmcnt(0)" ::: "memory");
    __builtin_amdgcn_sched_barrier(0);
    __builtin_amdgcn_s_barrier();
    if (t + 2 < NK) stage(cur, (t + 2) * 32);

    __builtin_amdgcn_s_setprio(1);
#pragma unroll
    for (int fi = 0; fi < 4; fi++)
#pragma unroll
      for (int fj = 0; fj < 4; fj++)
        acc[fi][fj] = __builtin_amdgcn_mfma_f32_16x16x32_bf16(af[fi], bfr[fj], acc[fi][fj], 0, 0, 0);
    __builtin_amdgcn_s_setprio(0);
  }

#pragma unroll
  for (int fi = 0; fi < 4; fi++) {
    int mBase = mt * 128 + wm + fi * 16 + ((lane >> 4) << 2);
#pragma unroll
    for (int r = 0; r < 4; r++) {
      int m = mBase + r;
      if (m < n_e) {
        float* orow = tmp + (size_t)(off_e + m) * DD + nt * 128 + wn;
#pragma unroll
        for (int fj = 0; fj < 4; fj++)
          orow[fj * 16 + (lane & 15)] = acc[fi][fj][r];
      }
    }
  }
}

// out[t] = p0*tmp[slot0] + p1*tmp[slot1]. one block per token, float4 per thread.
__global__ __launch_bounds__(256) void combine(
    const float* __restrict__ tmp, const int* __restrict__ slot,
    const float* __restrict__ top_p, float* __restrict__ out)
{
  int t = blockIdx.x, d = threadIdx.x;             // DD/4 == 256
  int s0 = slot[t * 2 + 0], s1 = slot[t * 2 + 1];
  float p0 = top_p[t * 2 + 0], p1 = top_p[t * 2 + 1];
  float4 a = ((const float4*)(tmp + (size_t)s0 * DD))[d];
  float4 b = ((const float4*)(tmp + (size_t)s1 * DD))[d];
  float4 o;
  o.x = p0 * a.x + p1 * b.x;
  o.y = p0 * a.y + p1 * b.y;
  o.z = p0 * a.z + p1 * b.z;
  o.w = p0 * a.w + p1 * b.w;
  ((float4*)(out + (size_t)t * DD))[d] = o;
}

extern "C" void kernel_launch(void* const* d_in, const int* in_sizes, int n_in,
                              void* d_out, int out_size, void* d_ws, size_t ws_size,
                              hipStream_t stream) {
  const float* x  = (const float*)d_in[0];
  const float* Wr = (const float*)d_in[1];
  const float* Wg = (const float*)d_in[2];
  const float* Wu = (const float*)d_in[3];
  const float* Wd = (const float*)d_in[4];

  float* out      = (float*)d_out;
  float* o_logits = out + (size_t)T_TOK * DD;
  float* o_probs  = o_logits + (size_t)T_TOK * EE;
  float* o_topi   = o_probs + (size_t)T_TOK * EE;

  char* w = (char*)d_ws;
  auto alloc = [&](size_t bytes) {
    char* p = w;
    w += (bytes + 255) & ~(size_t)255;
    return p;
  };
  unsigned short* Wgb = (unsigned short*)alloc((size_t)EE * HH * DD * 2);  // 41.9MB
  unsigned short* Wub = (unsigned short*)alloc((size_t)EE * HH * DD * 2);  // 41.9MB
  unsigned short* Wdb = (unsigned short*)alloc((size_t)EE * DD * HH * 2);
  unsigned short* xb  = (unsigned short*)alloc((size_t)T_TOK * DD * 2);
  unsigned short* hb  = (unsigned short*)alloc((size_t)PAIR_CAP * HH * 2);
  int*   top_e   = (int*)  alloc((size_t)T_TOK * 2 * 4);
  float* top_p   = (float*)alloc((size_t)T_TOK * 2 * 4);
  int*   counts  = (int*)  alloc(64);
  int*   offsets = (int*)  alloc(64);
  int*   cursors = (int*)  alloc(64);
  int*   list    = (int*)  alloc((size_t)PAIR_CAP * 4);
  int*   slot    = (int*)  alloc((size_t)T_TOK * 2 * 4);

  // tmp (pair outputs, fp32, 67.6MB) aliases Wgb+Wub (83.9MB) — dead after gemm_gateup.
  // stream-ordered: conv writes Wgb/Wub -> gateup reads -> gemm_down overwrites as tmp
  // -> combine reads tmp -> (next replay) conv rewrites. safe on a single stream.
  float* tmp = (float*)Wgb;

  zero_ints<<<1, 64, 0, stream>>>(counts, EE);
  {
    int nw4 = EE * HH * DD / 4;
    dim3 g((nw4 + 255) / 256, 3);
    conv_bf16_3<<<g, 256, 0, stream>>>(Wg, Wu, Wd, Wgb, Wub, Wdb, nw4);
  }
  router<<<T_TOK / 4, 256, 0, stream>>>(x, Wr, xb, o_logits, o_probs, o_topi, top_e, top_p, counts);
  mk_offsets<<<1, 64, 0, stream>>>(counts, offsets, cursors);
  scatter<<<T_TOK / 256, 256, 0, stream>>>(top_e, offsets, cursors, list, slot);
  gemm_gateup<<<EE * MT_MAX * NT1, 256, 0, stream>>>(xb, Wgb, Wub, list, offsets, counts, hb);
  gemm_down<<<EE * MT_MAX * NT2, 256, 0, stream>>>(hb, Wdb, offsets, counts, tmp);
  combine<<<T_TOK, 256, 0, stream>>>(tmp, slot, top_p, out);
}